// Round 7
// baseline (148.285 us; speedup 1.0000x reference)
//
#include <hip/hip_runtime.h>

// Problem constants (from reference): B=16, C=1, H=1024, W=1024, fp32.
#define HH 1024
#define WW 1024
#define W4 (WW / 4)
#define ROWS 4           // rows per pipeline stage
#define BANDS 4          // stages per block -> block covers 16 rows
#define NT 256

struct Stage {
    float4 tr[ROWS + 2];   // target rows hb-1 .. hb+ROWS
    float4 xr[ROWS];       // pred rows hb .. hb+ROWS-1
    float  halo[ROWS];     // vertical-max halo col for wave-boundary lanes
};

__device__ __forceinline__ float fmax3(float a, float b, float c) {
    return fmaxf(a, fmaxf(b, c));
}

__device__ __forceinline__ float loss_elem(float x, float t, float dil) {
    // target/dilated are exactly binary {0,1}: weight = 1 + 4*dil + 15*t
    // (t=1 => dil=1 => 20; t=0,dil=1 => 5; else 1) -- 2 fma vs 2 cmp+2 cndmask
    float w = fmaf(15.0f, t, fmaf(4.0f, dil, 1.0f));
    // BCE with logits: max(x,0) - x*t + log1p(exp(-|x|))
    // softplus via HW v_exp_f32 / v_log_f32 (absmax 0.0 since R2).
    float a  = fabsf(x);
    float sp = __logf(1.0f + __expf(-a));
    return w * (fmaxf(x, 0.0f) - x * t + sp);
}

__device__ __forceinline__ void load_stage(Stage& st,
        const float4* __restrict__ tg, const float4* __restrict__ pg,
        const float* __restrict__ timg, int hb, int tid, int lane, int c) {
    const float4 zero = make_float4(0.0f, 0.0f, 0.0f, 0.0f);
    st.tr[0] = (hb > 0) ? tg[(size_t)(hb - 1) * W4 + tid] : zero;
    #pragma unroll
    for (int r = 0; r < ROWS; ++r)
        st.tr[r + 1] = tg[(size_t)(hb + r) * W4 + tid];
    st.tr[ROWS + 1] = (hb + ROWS < HH) ? tg[(size_t)(hb + ROWS) * W4 + tid] : zero;
    #pragma unroll
    for (int r = 0; r < ROWS; ++r)
        st.xr[r] = pg[(size_t)(hb + r) * W4 + tid];

    #pragma unroll
    for (int r = 0; r < ROWS; ++r) st.halo[r] = 0.0f;
    if (lane == 0 || lane == 63) {          // patch cols c-1 / c+4 (2 lanes/wave)
        const int pc = (lane == 0) ? c - 1 : c + 4;
        if (pc >= 0 && pc < WW) {
            float pv[ROWS + 2];
            pv[0] = (hb > 0) ? timg[(size_t)(hb - 1) * WW + pc] : 0.0f;
            #pragma unroll
            for (int r = 0; r < ROWS; ++r)
                pv[r + 1] = timg[(size_t)(hb + r) * WW + pc];
            pv[ROWS + 1] = (hb + ROWS < HH)
                         ? timg[(size_t)(hb + ROWS) * WW + pc] : 0.0f;
            #pragma unroll
            for (int r = 0; r < ROWS; ++r)
                st.halo[r] = fmax3(pv[r], pv[r + 1], pv[r + 2]);
        }
    }
}

__device__ __forceinline__ float compute_stage(const Stage& st, int lane) {
    float s = 0.0f;
    #pragma unroll
    for (int r = 0; r < ROWS; ++r) {
        float4 a = st.tr[r], m = st.tr[r + 1], d = st.tr[r + 2];
        float4 vm = make_float4(fmax3(a.x, m.x, d.x), fmax3(a.y, m.y, d.y),
                                fmax3(a.z, m.z, d.z), fmax3(a.w, m.w, d.w));

        float l  = __shfl_up(vm.w, 1);
        float rr = __shfl_down(vm.x, 1);
        if (lane == 0)  l  = st.halo[r];
        if (lane == 63) rr = st.halo[r];

        float d0 = fmax3(l,    vm.x, vm.y);
        float d1 = fmax3(vm.x, vm.y, vm.z);
        float d2 = fmax3(vm.y, vm.z, vm.w);
        float d3 = fmax3(vm.z, vm.w, rr);

        float4 x = st.xr[r];
        s += loss_elem(x.x, m.x, d0);
        s += loss_elem(x.y, m.y, d1);
        s += loss_elem(x.z, m.z, d2);
        s += loss_elem(x.w, m.w, d3);
    }
    return s;
}

__global__ __launch_bounds__(NT) void dilatedweightBCE_main(
        const float* __restrict__ pred,
        const float* __restrict__ target,
        float* __restrict__ partial) {
    // One block per (image b, 16-row super-band) = 1024 blocks, all resident.
    // Software pipeline: double-buffered Stage structs -- while computing
    // stage k, stage k+1's 10 independent float4 loads are in flight.
    // R6's warm replays (0.13 MB HBM, same 43.5 us) proved latency-bound;
    // this overlaps the latency with the ~1500-cyc/stage compute.
    __shared__ float swave[4];

    const int tid  = threadIdx.x;
    const int lane = tid & 63;
    const int c    = tid * 4;
    const int b    = blockIdx.y;
    const int h0   = blockIdx.x * (ROWS * BANDS);

    const float* timg = target + (size_t)b * HH * WW;
    const float4* tg  = (const float4*)timg;
    const float4* pg  = (const float4*)(pred + (size_t)b * HH * WW);

    Stage sa, sb;
    load_stage(sa, tg, pg, timg, h0, tid, lane, c);

    float s = 0.0f;
    #pragma unroll
    for (int k = 0; k < BANDS; ++k) {
        if (k + 1 < BANDS)   // prefetch next stage into the other buffer
            load_stage((k & 1) ? sa : sb, tg, pg, timg,
                       h0 + (k + 1) * ROWS, tid, lane, c);
        s += compute_stage((k & 1) ? sb : sa, lane);
    }

    // wave (64-lane) shuffle reduction, then cross-wave via LDS
    #pragma unroll
    for (int off = 32; off > 0; off >>= 1)
        s += __shfl_down(s, off);

    const int wave = tid >> 6;
    if (lane == 0) swave[wave] = s;
    __syncthreads();
    if (tid == 0) {
        partial[blockIdx.y * gridDim.x + blockIdx.x] =
            swave[0] + swave[1] + swave[2] + swave[3];
    }
}

__global__ __launch_bounds__(NT) void dilatedweightBCE_reduce(
        const float* __restrict__ partial,
        float* __restrict__ out,
        int npart4,            // number of float4 chunks
        float inv_n) {
    __shared__ float swave[4];
    const int tid = threadIdx.x;

    float s = 0.0f;
    const float4* p4 = (const float4*)partial;
    for (int i = tid; i < npart4; i += NT) {
        float4 v = p4[i];
        s += v.x + v.y + v.z + v.w;
    }

    #pragma unroll
    for (int off = 32; off > 0; off >>= 1)
        s += __shfl_down(s, off);

    const int wave = tid >> 6;
    const int lane = tid & 63;
    if (lane == 0) swave[wave] = s;
    __syncthreads();
    if (tid == 0)
        out[0] = (swave[0] + swave[1] + swave[2] + swave[3]) * inv_n;
}

extern "C" void kernel_launch(void* const* d_in, const int* in_sizes, int n_in,
                              void* d_out, int out_size, void* d_ws, size_t ws_size,
                              hipStream_t stream) {
    const float* pred   = (const float*)d_in[0];
    const float* target = (const float*)d_in[1];
    float* out     = (float*)d_out;
    float* partial = (float*)d_ws;           // 1024 floats = 4 KB scratch

    const int n  = in_sizes[0];              // B*C*H*W
    const int Bn = n / (HH * WW);            // batch (16)
    const int nblocks = (HH / (ROWS * BANDS)) * Bn;   // 1024

    dim3 grid(HH / (ROWS * BANDS), Bn);
    dilatedweightBCE_main<<<grid, NT, 0, stream>>>(pred, target, partial);
    dilatedweightBCE_reduce<<<1, NT, 0, stream>>>(partial, out,
                                                  nblocks / 4, 1.0f / (float)n);
}